// Round 9
// baseline (60.777 us; speedup 1.0000x reference)
//
#include <hip/hip_runtime.h>

// TT-core contraction: C[a,c,i,k,b,d] = sum_j A[a,i,j,b] * B[c,j,k,d]
// A: [RA0, M, N, RA1=64], B: [RB0, N, P, RB1=16]
// C flat f32x4 index: (((a*RB0+c)*M+i)*P + k)*256 + tid   (tid = b*4+d4)
//
// Round 9 delta vs round 8: SEQUENTIAL store order. Loops are t-outer /
// k-inner so each block writes its 160KB output range monotonically
// (matching the 7TB/s fill kernel's walk), instead of the g,k,tl hop
// (+-20KB). B vectors re-read per (t,k) straight from global -- L1-resident
// broadcast, ~3% read overhead, hidden. No LDS, no barrier, plain stores.

typedef float f32x4 __attribute__((ext_vector_type(4)));

// f32x4 bases of each core's output region:
#define O0 0
#define O1 2048
#define O2 4196352
#define O3 14682112
#define O4 15730688

// block ranges: core2 first (dominant)
#define B2 1024            // 8192 t / NTT=8
#define B1 1024            // 8192 t / 8
#define B3 512             // 4096 t / 8
#define NBLK (B2 + B1 + B3 + 2)   // + core0, core4 = 2562

template<int M, int N, int P, int RB0, int NTT>
__device__ __forceinline__ void core_block(
    const float* __restrict__ A, const float* __restrict__ Bg,
    f32x4* __restrict__ out4, int bl, int tid)
{
    constexpr int SLAB = N * P * 4;               // f32x4 per B c-slab
    const int t0 = bl * NTT;
    const int b  = tid >> 2;
    const int d4 = tid & 3;

    // --- A into registers (one-time; 64B-granule, L1/L2-served) ---
    float areg[NTT][N];
#pragma unroll
    for (int t = 0; t < NTT; ++t) {
        const int tt = t0 + t;
        const int i  = tt & (M - 1);
        const int a  = tt / (M * RB0);
        const float* Ap = A + ((a * M + i) * N) * 64 + b;
#pragma unroll
        for (int j = 0; j < N; ++j) areg[t][j] = Ap[j * 64];
    }

    // --- compute + stores in strictly ascending address order ---
    const f32x4* Bg4 = reinterpret_cast<const f32x4*>(Bg);
#pragma unroll
    for (int t = 0; t < NTT; ++t) {
        const int tt = t0 + t;
        const int c  = (tt / M) & (RB0 - 1);
        const f32x4* Bc = Bg4 + c * SLAB + d4;
#pragma unroll
        for (int k = 0; k < P; ++k) {
            f32x4 Bk[N];
#pragma unroll
            for (int j = 0; j < N; ++j)
                Bk[j] = Bc[(j * P + k) * 4];      // L1 broadcast hit
            f32x4 acc = (f32x4)(0.f);
#pragma unroll
            for (int j = 0; j < N; ++j)
                acc += areg[t][j] * Bk[j];
            out4[(tt * P + k) * 256 + tid] = acc; // sequential walk
        }
    }
}

// core4: x4 [64,2,8,1] * w4 [16,8,1,1] -> out [1024,2,1,1]; o=(a*16+c)*2+i
__device__ __forceinline__ f32x4 core4_val(const float* __restrict__ x4,
                                           const float* __restrict__ w4,
                                           int w) {
    const int a  = w >> 3;
    const int c0 = (2 * w) & 15;
    const float* xr0 = x4 + (a * 2 + 0) * 8;
    const float* xr1 = x4 + (a * 2 + 1) * 8;
    const float* wc0 = w4 + c0 * 8;
    const float* wc1 = w4 + (c0 + 1) * 8;
    f32x4 acc = (f32x4)(0.f);
#pragma unroll
    for (int j = 0; j < 8; ++j) {
        acc.x = fmaf(xr0[j], wc0[j], acc.x);
        acc.y = fmaf(xr1[j], wc0[j], acc.y);
        acc.z = fmaf(xr0[j], wc1[j], acc.z);
        acc.w = fmaf(xr1[j], wc1[j], acc.w);
    }
    return acc;
}

__global__ __launch_bounds__(256) void fused_tt_kernel(
    const float* __restrict__ x0, const float* __restrict__ x1,
    const float* __restrict__ x2, const float* __restrict__ x3,
    const float* __restrict__ x4,
    const float* __restrict__ w0, const float* __restrict__ w1,
    const float* __restrict__ w2, const float* __restrict__ w3,
    const float* __restrict__ w4,
    float* __restrict__ out)
{
    const int blk = blockIdx.x;
    const int tid = threadIdx.x;
    f32x4* o4 = reinterpret_cast<f32x4*>(out);

    if (blk < B2) {
        core_block<8, 8, 5, 16, 8>(x2, w2, o4 + O2, blk, tid);
    } else if (blk < B2 + B1) {
        core_block<8, 4, 2, 16, 8>(x1, w1, o4 + O1, blk - B2, tid);
    } else if (blk < B2 + B1 + B3) {
        core_block<4, 4, 1, 16, 8>(x3, w3, o4 + O3, blk - B2 - B1, tid);
    } else if (blk == B2 + B1 + B3) {
        core_block<8, 3, 1, 1, 8>(x0, w0, o4 + O0, 0, tid);
    } else {
        // core4: 512 f32x4, one block, 2 iters
#pragma unroll
        for (int it = 0; it < 2; ++it) {
            const int w = it * 256 + tid;
            o4[O4 + w] = core4_val(x4, w4, w);
        }
    }
}

extern "C" void kernel_launch(void* const* d_in, const int* in_sizes, int n_in,
                              void* d_out, int out_size, void* d_ws, size_t ws_size,
                              hipStream_t stream) {
    const float* x0 = (const float*)d_in[0];
    const float* x1 = (const float*)d_in[1];
    const float* x2 = (const float*)d_in[2];
    const float* x3 = (const float*)d_in[3];
    const float* x4 = (const float*)d_in[4];
    const float* w0 = (const float*)d_in[5];
    const float* w1 = (const float*)d_in[6];
    const float* w2 = (const float*)d_in[7];
    const float* w3 = (const float*)d_in[8];
    const float* w4 = (const float*)d_in[9];
    float* out = (float*)d_out;

    fused_tt_kernel<<<NBLK, 256, 0, stream>>>(
        x0, x1, x2, x3, x4, w0, w1, w2, w3, w4, out);
}

// Round 10
// 44.915 us; speedup vs baseline: 1.3532x; 1.3532x over previous
//
#include <hip/hip_runtime.h>

// TT-core contraction: C[a,c,i,k,b,d] = sum_j A[a,i,j,b] * B[c,j,k,d]
// A: [RA0, M, N, RA1=64], B: [RB0, N, P, RB1=16]
// C flat f32x4 index: (((a*RB0+c)*M+i)*P + k)*256 + tid   (tid = b*4+d4)
//
// Round 10: ZERO broadcast global loads. Both A and B are staged to LDS with
// full-width coalesced dwordx4 loads (1KB/wave-instr); threads then fill
// registers from LDS (same-address 4-way broadcast reads = conflict-free,
// separate pipe). NTT=8 -> each block (t0 8-aligned) has a single (a,c) for
// NG=1 cores; 2562 total blocks. Compute keeps the proven g,k,tl order with
// B hoisted to registers per (g,k). Plain stores (R7: cached-writeback beats
// nt by 20%). Theory: R9's +16us from 240 extra broadcast loads/wave shows
// VMEM return bus is the co-limiter with the store stream.

typedef float f32x4 __attribute__((ext_vector_type(4)));

// f32x4 bases of each core's output region:
#define O0 0
#define O1 2048
#define O2 4196352
#define O3 14682112
#define O4 15730688

#define B2 1024            // 8192 t / NTT=8
#define B1 1024
#define B3 512
#define NBLK (B2 + B1 + B3 + 2)   // + core0, core4 = 2562

template<int M, int N, int P, int RB0, int NTT>
__device__ __forceinline__ void core_block(
    const float* __restrict__ A, const float* __restrict__ Bg,
    f32x4* __restrict__ out4, int bl, int tid,
    float* __restrict__ Als, f32x4* __restrict__ Bls)
{
    constexpr int SLAB = N * P * 4;               // f32x4 per B c-slab
    constexpr int NTC  = (NTT < M) ? NTT : M;     // t's sharing one (a,c)
    constexpr int NG   = NTT / NTC;               // distinct c groups
    constexpr int AV   = M * N * 16;              // f32x4 in A a-slab
    const int t0  = bl * NTT;
    const int b   = tid >> 2;
    const int d4  = tid & 3;
    const int ac0 = t0 / M;                       // first a*RB0+c
    const int a   = ac0 / RB0;                    // same for all NG groups

    // --- stage A a-slab to LDS (coalesced dwordx4, no broadcast) ---
    const f32x4* Ag4 = reinterpret_cast<const f32x4*>(A + a * (M * N * 64));
    f32x4* Als4 = reinterpret_cast<f32x4*>(Als);
#pragma unroll
    for (int r = tid; r < AV; r += 256) Als4[r] = Ag4[r];

    // --- stage B c-slab(s) to LDS ---
    const f32x4* Bg4 = reinterpret_cast<const f32x4*>(Bg);
#pragma unroll
    for (int g = 0; g < NG; ++g) {
        const int c = (ac0 + g) & (RB0 - 1);
        if (tid < SLAB) Bls[g * SLAB + tid] = Bg4[c * SLAB + tid];
    }
    __syncthreads();

    // --- A into registers from LDS (4-way same-address broadcast) ---
    float areg[NTT][N];
#pragma unroll
    for (int t = 0; t < NTT; ++t) {
        const int i = t & (M - 1);
#pragma unroll
        for (int j = 0; j < N; ++j)
            areg[t][j] = Als[((i * N + j) << 6) + b];
    }

    // --- compute + stores; B hoisted per (group,k), g/k/tl order ---
#pragma unroll
    for (int g = 0; g < NG; ++g) {
#pragma unroll
        for (int k = 0; k < P; ++k) {
            f32x4 Bk[N];
#pragma unroll
            for (int j = 0; j < N; ++j)
                Bk[j] = Bls[g * SLAB + (j * P + k) * 4 + d4];
#pragma unroll
            for (int tl = 0; tl < NTC; ++tl) {
                const int t = g * NTC + tl;
                f32x4 acc = (f32x4)(0.f);
#pragma unroll
                for (int j = 0; j < N; ++j)
                    acc += areg[t][j] * Bk[j];
                out4[((t0 + t) * P + k) * 256 + tid] = acc;
            }
        }
    }
}

// core4: x4 [64,2,8,1] * w4 [16,8,1,1] -> out [1024,2,1,1]; o=(a*16+c)*2+i
__device__ __forceinline__ f32x4 core4_val(const float* __restrict__ x4,
                                           const float* __restrict__ w4,
                                           int w) {
    const int a  = w >> 3;
    const int c0 = (2 * w) & 15;
    const float* xr0 = x4 + (a * 2 + 0) * 8;
    const float* xr1 = x4 + (a * 2 + 1) * 8;
    const float* wc0 = w4 + c0 * 8;
    const float* wc1 = w4 + (c0 + 1) * 8;
    f32x4 acc = (f32x4)(0.f);
#pragma unroll
    for (int j = 0; j < 8; ++j) {
        acc.x = fmaf(xr0[j], wc0[j], acc.x);
        acc.y = fmaf(xr1[j], wc0[j], acc.y);
        acc.z = fmaf(xr0[j], wc1[j], acc.z);
        acc.w = fmaf(xr1[j], wc1[j], acc.w);
    }
    return acc;
}

__global__ __launch_bounds__(256) void fused_tt_kernel(
    const float* __restrict__ x0, const float* __restrict__ x1,
    const float* __restrict__ x2, const float* __restrict__ x3,
    const float* __restrict__ x4,
    const float* __restrict__ w0, const float* __restrict__ w1,
    const float* __restrict__ w2, const float* __restrict__ w3,
    const float* __restrict__ w4,
    float* __restrict__ out)
{
    __shared__ float Als[4096];     // 16KB: core2 a-slab (8*8*64)
    __shared__ f32x4 Bls[320];      // 5KB
    const int blk = blockIdx.x;
    const int tid = threadIdx.x;
    f32x4* o4 = reinterpret_cast<f32x4*>(out);

    if (blk < B2) {
        core_block<8, 8, 5, 16, 8>(x2, w2, o4 + O2, blk, tid, Als, Bls);
    } else if (blk < B2 + B1) {
        core_block<8, 4, 2, 16, 8>(x1, w1, o4 + O1, blk - B2, tid, Als, Bls);
    } else if (blk < B2 + B1 + B3) {
        core_block<4, 4, 1, 16, 8>(x3, w3, o4 + O3, blk - B2 - B1, tid, Als, Bls);
    } else if (blk == B2 + B1 + B3) {
        core_block<8, 3, 1, 1, 8>(x0, w0, o4 + O0, 0, tid, Als, Bls);
    } else {
        // core4: 512 f32x4, one block, 2 iters
#pragma unroll
        for (int it = 0; it < 2; ++it) {
            const int w = it * 256 + tid;
            o4[O4 + w] = core4_val(x4, w4, w);
        }
    }
}

extern "C" void kernel_launch(void* const* d_in, const int* in_sizes, int n_in,
                              void* d_out, int out_size, void* d_ws, size_t ws_size,
                              hipStream_t stream) {
    const float* x0 = (const float*)d_in[0];
    const float* x1 = (const float*)d_in[1];
    const float* x2 = (const float*)d_in[2];
    const float* x3 = (const float*)d_in[3];
    const float* x4 = (const float*)d_in[4];
    const float* w0 = (const float*)d_in[5];
    const float* w1 = (const float*)d_in[6];
    const float* w2 = (const float*)d_in[7];
    const float* w3 = (const float*)d_in[8];
    const float* w4 = (const float*)d_in[9];
    float* out = (float*)d_out;

    fused_tt_kernel<<<NBLK, 256, 0, stream>>>(
        x0, x1, x2, x3, x4, w0, w1, w2, w3, w4, out);
}

// Round 11
// 43.570 us; speedup vs baseline: 1.3949x; 1.0309x over previous
//
#include <hip/hip_runtime.h>

// TT-core contraction: C[a,c,i,k,b,d] = sum_j A[a,i,j,b] * B[c,j,k,d]
// A: [RA0, M, N, RA1=64], B: [RB0, N, P, RB1=16]
// C flat f32x4 index: (((a*RB0+c)*M+i)*P + k)*256 + tid   (tid = b*4+d4)
//
// FINAL (= round 7, best measured: 43.6us ~ 5.8 TB/s effective write).
// Ladder: 72us (naive-structure, input L1/L2 churn doubled fabric traffic)
//  -> 53.4 (block-local A-regs + B-LDS, churn eliminated)
//  -> 43.6 (plain stores; nt forced HBM at 4.8TB/s, cached writeback wins)
// Null A/Bs: persistent grid (R2), B-hoist 4x fewer LDS reads (R6), no-LDS/
// no-barrier (R8), sequential store order (R9: -16us regression from
// broadcast-load amplification, reverted), full zero-broadcast staging (R10).
// Mandatory 245.8MB write at fill-kernel's 6.6-7.0TB/s = 35-37us + launch
// overhead -> practical floor ~38-42us; this kernel is within a few % of it.

typedef float f32x4 __attribute__((ext_vector_type(4)));

// f32x4 bases of each core's output region:
#define O0 0
#define O1 2048
#define O2 4196352
#define O3 14682112
#define O4 15730688

// block ranges: core2 first (dominant)
#define B2 2048            // 40960 outers / (NT=4 * P=5)
#define B1 1024            // 16384 / (8*2)
#define B3 512             // 4096 / (8*1)
#define NBLK (B2 + B1 + B3 + 2)   // + core0, core4

template<int M, int N, int P, int RB0, int NTT>
__device__ __forceinline__ void core_block(
    const float* __restrict__ A, const float* __restrict__ Bg,
    f32x4* __restrict__ out4, int bl, f32x4* __restrict__ Bl, int tid)
{
    constexpr int SLAB = N * P * 4;               // f32x4 per B c-slab
    constexpr int NTC  = (NTT < M) ? NTT : M;     // t's sharing one c
    constexpr int NG   = NTT / NTC;               // distinct c groups
    const int t0 = bl * NTT;
    const int b  = tid >> 2;
    const int d4 = tid & 3;

    // --- A into registers (one-time; 64B-granule, L1/L2-served) ---
    float areg[NTT][N];
#pragma unroll
    for (int t = 0; t < NTT; ++t) {
        const int tt = t0 + t;
        const int i  = tt & (M - 1);
        const int a  = tt / (M * RB0);
        const float* Ap = A + ((a * M + i) * N) * 64 + b;
#pragma unroll
        for (int j = 0; j < N; ++j) areg[t][j] = Ap[j * 64];
    }

    // --- distinct B c-slabs into LDS ---
    const f32x4* Bg4 = reinterpret_cast<const f32x4*>(Bg);
#pragma unroll
    for (int g = 0; g < NG; ++g) {
        const int c = ((t0 + g * NTC) / M) & (RB0 - 1);
        for (int r = tid; r < SLAB; r += 256)
            Bl[g * SLAB + r] = Bg4[c * SLAB + r];
    }
    __syncthreads();

    // --- compute + streaming stores; B hoisted per (group,k) ---
#pragma unroll
    for (int g = 0; g < NG; ++g) {
#pragma unroll
        for (int k = 0; k < P; ++k) {
            f32x4 Bk[N];
#pragma unroll
            for (int j = 0; j < N; ++j)
                Bk[j] = Bl[g * SLAB + (j * P + k) * 4 + d4];
#pragma unroll
            for (int tl = 0; tl < NTC; ++tl) {
                const int t = g * NTC + tl;
                f32x4 acc = (f32x4)(0.f);
#pragma unroll
                for (int j = 0; j < N; ++j)
                    acc += areg[t][j] * Bk[j];
                out4[((t0 + t) * P + k) * 256 + tid] = acc;
            }
        }
    }
}

// core4: x4 [64,2,8,1] * w4 [16,8,1,1] -> out [1024,2,1,1]; o=(a*16+c)*2+i
__device__ __forceinline__ f32x4 core4_val(const float* __restrict__ x4,
                                           const float* __restrict__ w4,
                                           int w) {
    const int a  = w >> 3;
    const int c0 = (2 * w) & 15;
    const float* xr0 = x4 + (a * 2 + 0) * 8;
    const float* xr1 = x4 + (a * 2 + 1) * 8;
    const float* wc0 = w4 + c0 * 8;
    const float* wc1 = w4 + (c0 + 1) * 8;
    f32x4 acc = (f32x4)(0.f);
#pragma unroll
    for (int j = 0; j < 8; ++j) {
        acc.x = fmaf(xr0[j], wc0[j], acc.x);
        acc.y = fmaf(xr1[j], wc0[j], acc.y);
        acc.z = fmaf(xr0[j], wc1[j], acc.z);
        acc.w = fmaf(xr1[j], wc1[j], acc.w);
    }
    return acc;
}

__global__ __launch_bounds__(256) void fused_tt_kernel(
    const float* __restrict__ x0, const float* __restrict__ x1,
    const float* __restrict__ x2, const float* __restrict__ x3,
    const float* __restrict__ x4,
    const float* __restrict__ w0, const float* __restrict__ w1,
    const float* __restrict__ w2, const float* __restrict__ w3,
    const float* __restrict__ w4,
    float* __restrict__ out)
{
    __shared__ f32x4 Bl[320];              // core2: 1 slab x 160 f32x4 = 2.5KB
    const int blk = blockIdx.x;
    const int tid = threadIdx.x;
    f32x4* o4 = reinterpret_cast<f32x4*>(out);

    if (blk < B2) {
        core_block<8, 8, 5, 16, 4>(x2, w2, o4 + O2, blk, Bl, tid);
    } else if (blk < B2 + B1) {
        core_block<8, 4, 2, 16, 8>(x1, w1, o4 + O1, blk - B2, Bl, tid);
    } else if (blk < B2 + B1 + B3) {
        core_block<4, 4, 1, 16, 8>(x3, w3, o4 + O3, blk - B2 - B1, Bl, tid);
    } else if (blk == B2 + B1 + B3) {
        core_block<8, 3, 1, 1, 8>(x0, w0, o4 + O0, 0, Bl, tid);
    } else {
        // core4: 512 f32x4, one block, 2 iters
#pragma unroll
        for (int it = 0; it < 2; ++it) {
            const int w = it * 256 + tid;
            o4[O4 + w] = core4_val(x4, w4, w);
        }
    }
}

extern "C" void kernel_launch(void* const* d_in, const int* in_sizes, int n_in,
                              void* d_out, int out_size, void* d_ws, size_t ws_size,
                              hipStream_t stream) {
    const float* x0 = (const float*)d_in[0];
    const float* x1 = (const float*)d_in[1];
    const float* x2 = (const float*)d_in[2];
    const float* x3 = (const float*)d_in[3];
    const float* x4 = (const float*)d_in[4];
    const float* w0 = (const float*)d_in[5];
    const float* w1 = (const float*)d_in[6];
    const float* w2 = (const float*)d_in[7];
    const float* w3 = (const float*)d_in[8];
    const float* w4 = (const float*)d_in[9];
    float* out = (float*)d_out;

    fused_tt_kernel<<<NBLK, 256, 0, stream>>>(
        x0, x1, x2, x3, x4, w0, w1, w2, w3, w4, out);
}